// Round 2
// baseline (325.288 us; speedup 1.0000x reference)
//
#include <hip/hip_runtime.h>
#include <hip/hip_bf16.h>
#include <stdint.h>

#define AS_GLOBAL __attribute__((address_space(1)))
#define AS_LDS    __attribute__((address_space(3)))

typedef __attribute__((ext_vector_type(8))) short  bf16x8;
typedef __attribute__((ext_vector_type(4))) float  f32x4;
typedef __attribute__((ext_vector_type(8))) short  s16x8;

__device__ __forceinline__ void gload_lds16(const void* g, void* l) {
    __builtin_amdgcn_global_load_lds((AS_GLOBAL const void*)g, (AS_LDS void*)l, 16, 0, 0);
}

// Cast 8 fp32 -> 8 bf16 (one 16B store), pair index p into region (s,d).
__device__ __forceinline__ void cast_pair(const float* __restrict__ s,
                                          __hip_bfloat16* __restrict__ d, long p) {
    f32x4 a = ((const f32x4*)s)[p * 2];
    f32x4 b = ((const f32x4*)s)[p * 2 + 1];
    union { s16x8 p8; __hip_bfloat16 h[8]; } u;
    u.h[0] = __float2bfloat16(a.x); u.h[1] = __float2bfloat16(a.y);
    u.h[2] = __float2bfloat16(a.z); u.h[3] = __float2bfloat16(a.w);
    u.h[4] = __float2bfloat16(b.x); u.h[5] = __float2bfloat16(b.y);
    u.h[6] = __float2bfloat16(b.z); u.h[7] = __float2bfloat16(b.w);
    ((s16x8*)d)[p] = u.p8;
}

// x cast only: 1024x2048 fp32 -> bf16. 262144 pairs, 1024 blocks x 256, 1 pair each.
__global__ void cast_x_k(const float* __restrict__ x, __hip_bfloat16* __restrict__ xb) {
    long p = (long)blockIdx.x * 256 + threadIdx.x;
    cast_pair(x, xb, p);
}

// Split-K GEMM: P[z][M,N] = bf16( A[M,k0:k1] @ B[N,k0:k1]^T ).
//   A: bf16, staged via global_load_lds (DMA, linear dest, pre-swizzled source).
//   B: *fp32*, reg-staged: global_load_dwordx4 x2 -> cvt bf16 -> ds_write_b128
//      directly to the swizzled slot. Eliminates the separate weight-cast
//      kernels/planes and their 120 MB round-trip (R1 post-mortem: the fused
//      cast stream, not the GEMM structure, was the bottleneck of the worst
//      dispatch).
// Single-buffered 32 KB LDS, launch_bounds(256,4) -> 4 blocks/CU; split-K
// sized so the grid fills 4/CU (GEMM1/2: S=4 -> 1024 blocks).
// 128x128 tile, BK=64, 4 waves, 4x4 16x16x32 MFMA. XOR-swizzled LDS
// (conflict-free, verified): source granule g of row r lives at slot g^(r&7).
__global__ __launch_bounds__(256, 4)
void gemm_bf(const __hip_bfloat16* __restrict__ A,
             const float* __restrict__ Bf,
             __hip_bfloat16* __restrict__ P,
             const int M, const int N, const int kchunk, const int S)
{
    __shared__ __hip_bfloat16 As[128 * 64];
    __shared__ __hip_bfloat16 Bs[128 * 64];

    const int tid = threadIdx.x;
    int bn = blockIdx.x, bm = blockIdx.y;
    const int kz = blockIdx.z;

    // XCD-chunked remap within this z-plane (plane size % 8 == 0 in all launches).
    const int Gx = gridDim.x;
    if ((Gx & 7) == 0) {
        const int bnx = Gx >> 3;
        const int lid = bm * Gx + bn;
        const int xcd = lid & 7;
        const int ix  = lid >> 3;
        bn = xcd * bnx + (ix % bnx);
        bm = ix / bnx;
    }

    const int lane = tid & 63;
    const int wave = tid >> 6;
    const int wm   = wave >> 1, wn = wave & 1;
    const int lm   = lane & 15, lq = lane >> 4;

    const int K  = kchunk * S;
    const int k0 = kz * kchunk;

    const int rlo  = lane >> 3;                  // row within an 8-row staging chunk
    const int g    = lane & 7;                   // source granule (8 elems)
    const int gsw8 = ((g ^ rlo) << 3);           // swizzled slot -> element offset

    const __hip_bfloat16* Ag = A  + (size_t)(bm * 128) * K;
    const float*          Bg = Bf + (size_t)(bn * 128) * K;

    f32x4 acc[4][4];
    #pragma unroll
    for (int i = 0; i < 4; ++i)
        #pragma unroll
        for (int j = 0; j < 4; ++j)
            acc[i][j] = (f32x4){0.f, 0.f, 0.f, 0.f};

    for (int kt = k0; kt < k0 + kchunk; kt += 64) {
        __syncthreads();
        // B (fp32): issue all 8 global dwordx4 loads first (oldest in VMEM queue).
        f32x4 bl[4][2];
        #pragma unroll
        for (int c = 0; c < 4; ++c) {
            const int row = (wave * 4 + c) * 8 + rlo;
            const float* p = Bg + (size_t)row * K + kt + g * 8;
            bl[c][0] = *(const f32x4*)p;
            bl[c][1] = *(const f32x4*)(p + 4);
        }
        // A (bf16): DMA to LDS; issued after B loads, so the cvt/write wait
        // below (vmcnt) only drains the B loads, leaving these in flight
        // until the closing barrier.
        #pragma unroll
        for (int c = 0; c < 4; ++c) {
            const int chunk = wave * 4 + c;
            const int row   = chunk * 8 + rlo;
            gload_lds16(Ag + (size_t)row * K + kt + gsw8, As + chunk * 512);
        }
        // B: cvt fp32->bf16, write 16B granule to its swizzled slot.
        #pragma unroll
        for (int c = 0; c < 4; ++c) {
            const int chunk = wave * 4 + c;
            union { s16x8 p8; __hip_bfloat16 h[8]; } u;
            u.h[0] = __float2bfloat16(bl[c][0].x); u.h[1] = __float2bfloat16(bl[c][0].y);
            u.h[2] = __float2bfloat16(bl[c][0].z); u.h[3] = __float2bfloat16(bl[c][0].w);
            u.h[4] = __float2bfloat16(bl[c][1].x); u.h[5] = __float2bfloat16(bl[c][1].y);
            u.h[6] = __float2bfloat16(bl[c][1].z); u.h[7] = __float2bfloat16(bl[c][1].w);
            *(s16x8*)(Bs + chunk * 512 + rlo * 64 + gsw8) = u.p8;
        }
        __syncthreads();
        #pragma unroll
        for (int kk = 0; kk < 2; ++kk) {
            // granule G = kk*4+lq of row lives at slot G^(row&7); row&7 == lm&7
            const int sl = (((kk * 4 + lq) ^ (lm & 7)) << 3);
            bf16x8 af[4], bq[4];
            #pragma unroll
            for (int i = 0; i < 4; ++i)
                af[i] = *(const bf16x8*)(As + (wm * 64 + i * 16 + lm) * 64 + sl);
            #pragma unroll
            for (int j = 0; j < 4; ++j)
                bq[j] = *(const bf16x8*)(Bs + (wn * 64 + j * 16 + lm) * 64 + sl);
            #pragma unroll
            for (int i = 0; i < 4; ++i)
                #pragma unroll
                for (int j = 0; j < 4; ++j)
                    acc[i][j] = __builtin_amdgcn_mfma_f32_16x16x32_bf16(af[i], bq[j], acc[i][j], 0, 0, 0);
        }
    }

    __hip_bfloat16* Pz = P + (size_t)kz * M * N;
    const int row0 = bm * 128 + wm * 64;
    const int colb = bn * 128 + wn * 64 + lm;
    #pragma unroll
    for (int j = 0; j < 4; ++j) {
        const int col = colb + j * 16;
        #pragma unroll
        for (int i = 0; i < 4; ++i)
            #pragma unroll
            for (int r = 0; r < 4; ++r) {
                const int row = row0 + i * 16 + lq * 4 + r;
                Pz[(size_t)row * N + col] = __float2bfloat16(acc[i][j][r]);
            }
    }
}

// T-collapse: za = sum_{u=1..T} w_u * relu(c_u*y + b2), where
// c_u = 1-beta1^u, w_u = (1-b2f)(1-b3f)*g_u, g_u = b2f*g_{u+1} + b3f^(T-u), g_T=1.
template <int TT>
__device__ __forceinline__ void tcollapse_coef(float be1, float be2, float be3,
                                               float* __restrict__ c, float* __restrict__ w) {
    float g[TT + 1];
    g[TT] = 1.f;
    float p3 = 1.f;
    #pragma unroll
    for (int u = TT - 1; u >= 1; --u) {
        p3 *= be3;
        g[u] = be2 * g[u + 1] + p3;
    }
    const float s = (1.f - be2) * (1.f - be3);
    float p1 = 1.f;
    #pragma unroll
    for (int u = 1; u <= TT; ++u) {
        p1 *= be1;
        c[u - 1] = 1.f - p1;
        w[u - 1] = s * g[u];
    }
}

// Sum S bf16 split-K partials (16B loads, fp32 accumulate) + epilogue. 8 elems/thread.
// MODE 0: bf16 out = relu(sum + bias)            (layer1 -> D1)
// MODE 1: bf16 out = T-collapse(y=sum, b2)       (layer2 -> Z)
// MODE 2: f32  out = sum + (1-beta3^T)*bias      (layer3 -> s3_T)
template <int MODE>
__global__ void reduce_k(const __hip_bfloat16* __restrict__ P, const int S,
                         void* __restrict__ outv, const long MN, const int N,
                         const float* __restrict__ bias,
                         const float* __restrict__ b_taus,
                         const int* __restrict__ Tp)
{
    long i8 = (long)blockIdx.x * 256 + threadIdx.x;   // 8-element group, exact cover
    long i  = i8 * 8;
    float a[8] = {0.f, 0.f, 0.f, 0.f, 0.f, 0.f, 0.f, 0.f};
    for (int s = 0; s < S; ++s) {
        union { s16x8 p8; __hip_bfloat16 h[8]; } u;
        u.p8 = *(const s16x8*)(P + (size_t)s * MN + i);
        #pragma unroll
        for (int c = 0; c < 8; ++c) a[c] += __bfloat162float(u.h[c]);
    }
    const int col = (int)(i % N);
    float bb[8];
    #pragma unroll
    for (int c = 0; c < 8; ++c) bb[c] = bias[col + c];

    if constexpr (MODE == 0) {
        union { s16x8 p8; __hip_bfloat16 h[8]; } u;
        #pragma unroll
        for (int c = 0; c < 8; ++c)
            u.h[c] = __float2bfloat16(fmaxf(a[c] + bb[c], 0.f));
        ((s16x8*)outv)[i8] = u.p8;
    } else if constexpr (MODE == 1) {
        const int   T   = *Tp;
        const float be1 = 1.f / (1.f + expf(-b_taus[0]));
        const float be2 = 1.f / (1.f + expf(-b_taus[1]));
        const float be3 = 1.f / (1.f + expf(-b_taus[2]));
        union { s16x8 p8; __hip_bfloat16 h[8]; } u;
        if (T == 10) {
            float c10[10], w10[10];
            tcollapse_coef<10>(be1, be2, be3, c10, w10);
            #pragma unroll
            for (int c = 0; c < 8; ++c) {
                float za = 0.f;
                #pragma unroll
                for (int t = 0; t < 10; ++t)
                    za += w10[t] * fmaxf(fmaf(c10[t], a[c], bb[c]), 0.f);
                u.h[c] = __float2bfloat16(za);
            }
        } else {
            #pragma unroll
            for (int c = 0; c < 8; ++c) {
                float p1 = 1.f, s2 = 0.f, za = 0.f;
                for (int t = 0; t < T; ++t) {
                    p1 *= be1;
                    const float d2 = fmaxf(fmaf(1.f - p1, a[c], bb[c]), 0.f);
                    s2 = be2 * s2 + (1.f - be2) * d2;
                    za = be3 * za + (1.f - be3) * s2;
                }
                u.h[c] = __float2bfloat16(za);
            }
        }
        ((s16x8*)outv)[i8] = u.p8;
    } else {
        const int   T   = *Tp;
        const float be3 = 1.f / (1.f + expf(-b_taus[2]));
        float g = 0.f;
        for (int t = 0; t < T; ++t) g = be3 * g + (1.f - be3);   // 1 - beta3^T
        f32x4 o0, o1;
        o0.x = a[0] + g * bb[0]; o0.y = a[1] + g * bb[1];
        o0.z = a[2] + g * bb[2]; o0.w = a[3] + g * bb[3];
        o1.x = a[4] + g * bb[4]; o1.y = a[5] + g * bb[5];
        o1.z = a[6] + g * bb[6]; o1.w = a[7] + g * bb[7];
        ((f32x4*)outv)[i8 * 2]     = o0;
        ((f32x4*)outv)[i8 * 2 + 1] = o1;
    }
}

extern "C" void kernel_launch(void* const* d_in, const int* in_sizes, int n_in,
                              void* d_out, int out_size, void* d_ws, size_t ws_size,
                              hipStream_t stream) {
    const float* x      = (const float*)d_in[0];
    const float* W1     = (const float*)d_in[1];
    const float* b1     = (const float*)d_in[2];
    const float* W2     = (const float*)d_in[3];
    const float* b2     = (const float*)d_in[4];
    const float* W3     = (const float*)d_in[5];
    const float* b3     = (const float*)d_in[6];
    const float* b_taus = (const float*)d_in[7];
    const int*   Tp     = (const int*)d_in[8];

    const int B = 1024, DIN = 2048, H1 = 4096, H2 = 4096, DOUT = 1024;
    const long MB = 1024 * 1024;

    // Arena (100 MB, no aliasing): xb 0 (4MB), D1b 4 (8MB), Sb 12 (8MB),
    // P1 20 (32MB), P2 52 (32MB), P3 84 (16MB)   [bf16]
    char* ws = (char*)d_ws;
    __hip_bfloat16* xb  = (__hip_bfloat16*)(ws + 0);
    __hip_bfloat16* D1b = (__hip_bfloat16*)(ws + 4 * MB);
    __hip_bfloat16* Sb  = (__hip_bfloat16*)(ws + 12 * MB);
    __hip_bfloat16* P1  = (__hip_bfloat16*)(ws + 20 * MB);
    __hip_bfloat16* P2  = (__hip_bfloat16*)(ws + 52 * MB);
    __hip_bfloat16* P3  = (__hip_bfloat16*)(ws + 84 * MB);

    // x -> bf16 (8 MB read, 4 MB write; gates only GEMM1's A operand)
    cast_x_k<<<dim3(1024), dim3(256), 0, stream>>>(x, xb);

    // Layer 1: A=xb bf16, B=W1 fp32 reg-staged. S=4 -> 1024 blocks (4/CU).
    gemm_bf<<<dim3(H1 / 128, B / 128, 4), 256, 0, stream>>>(
        xb, W1, P1, B, H1, DIN / 4, 4);
    reduce_k<0><<<dim3(2048), 256, 0, stream>>>(P1, 4, (void*)D1b, (long)B * H1, H1, b1, nullptr, nullptr);

    // Layer 2: A=D1b bf16, B=W2 fp32 reg-staged. S=4 -> 1024 blocks (4/CU).
    gemm_bf<<<dim3(H2 / 128, B / 128, 4), 256, 0, stream>>>(
        D1b, W2, P2, B, H2, H1 / 4, 4);
    reduce_k<1><<<dim3(2048), 256, 0, stream>>>(P2, 4, (void*)Sb, (long)B * H2, H2, b2, b_taus, Tp);

    // Layer 3: A=Sb bf16, B=W3 fp32 reg-staged. S=8 -> 512 blocks.
    gemm_bf<<<dim3(DOUT / 128, B / 128, 8), 256, 0, stream>>>(
        Sb, W3, P3, B, DOUT, H2 / 8, 8);
    reduce_k<2><<<dim3(512), 256, 0, stream>>>(P3, 8, d_out, (long)B * DOUT, DOUT, b3, b_taus, Tp);
}

// Round 3
// 265.615 us; speedup vs baseline: 1.2247x; 1.2247x over previous
//
#include <hip/hip_runtime.h>
#include <hip/hip_bf16.h>
#include <stdint.h>

#define AS_GLOBAL __attribute__((address_space(1)))
#define AS_LDS    __attribute__((address_space(3)))

typedef __attribute__((ext_vector_type(8))) short  bf16x8;
typedef __attribute__((ext_vector_type(4))) float  f32x4;
typedef __attribute__((ext_vector_type(4))) short  s16x4;
typedef __attribute__((ext_vector_type(8))) short  s16x8;

__device__ __forceinline__ void gload_lds16(const void* g, void* l) {
    __builtin_amdgcn_global_load_lds((AS_GLOBAL const void*)g, (AS_LDS void*)l, 16, 0, 0);
}

// Cast 8 fp32 -> 8 bf16 (one 16B store), pair index p into region (s,d).
__device__ __forceinline__ void cast_pair(const float* __restrict__ s,
                                          __hip_bfloat16* __restrict__ d, long p) {
    f32x4 a = ((const f32x4*)s)[p * 2];
    f32x4 b = ((const f32x4*)s)[p * 2 + 1];
    union { s16x8 p8; __hip_bfloat16 h[8]; } u;
    u.h[0] = __float2bfloat16(a.x); u.h[1] = __float2bfloat16(a.y);
    u.h[2] = __float2bfloat16(a.z); u.h[3] = __float2bfloat16(a.w);
    u.h[4] = __float2bfloat16(b.x); u.h[5] = __float2bfloat16(b.y);
    u.h[6] = __float2bfloat16(b.z); u.h[7] = __float2bfloat16(b.w);
    ((s16x8*)d)[p] = u.p8;
}

// castA: x (262144 pairs) + W1 (1048576 pairs) = 1310720 pairs; 1280 blocks x 256 x 4 iters.
__global__ void cast_a_k(const float* __restrict__ x,  __hip_bfloat16* __restrict__ xb,
                         const float* __restrict__ W1, __hip_bfloat16* __restrict__ W1b) {
    const long nx = 262144, ntot = 1310720, stride = 1280 * 256;
    long t = (long)blockIdx.x * 256 + threadIdx.x;
    for (long p = t; p < ntot; p += stride) {
        if (p < nx) cast_pair(x, xb, p);
        else        cast_pair(W1, W1b, p - nx);
    }
}

// Split-K GEMM: P[z][M,N] = bf16( A[M,k0:k1] @ B[N,k0:k1]^T ).
// grid = (N/128, M/128, CP + S), CP = FUSECAST leading cast planes (z < CP).
// R3 (post-mortem of R0..R2): R0 body verbatim (single-buffer, global_load_lds
// both operands -- reg-staging regressed 2x in R2; dbuf was neutral in R1),
// with the one evidence-backed change: launch_bounds(256,4). R2 proved (256,4)
// compiles clean (60 VGPR, 40% occupancy). R0's (256,3) left GEMM1 at only
// 2 GEMM blocks/CU (cast block held the 3rd slot; 318 TF) while GEMM2 at
// ~3.2 blocks/CU hit >=640 TF -> throughput here scales with co-resident
// blocks. Now: GEMM1 S=4 (+1 cast plane, backfills to 4/CU once cast
// retires), GEMM2 S=4 clean 4/CU round, GEMM3 S=16.
// 128x128 tile, BK=64, 4 waves, 4x4 16x16x32 MFMA. XOR-swizzled LDS
// (conflict-free, verified): granule g of row r stored at slot g^(r&7).
template <int FUSECAST>
__global__ __launch_bounds__(256, 4)
void gemm_btk(const __hip_bfloat16* __restrict__ A,
              const __hip_bfloat16* __restrict__ Bm,
              __hip_bfloat16* __restrict__ P,
              const int M, const int N, const int kchunk, const int S,
              const float* __restrict__ cs1, __hip_bfloat16* __restrict__ cd1, const long cn1,
              const float* __restrict__ cs2, __hip_bfloat16* __restrict__ cd2, const long cn2)
{
    __shared__ __hip_bfloat16 As[128 * 64];
    __shared__ __hip_bfloat16 Bs[128 * 64];

    const int tid = threadIdx.x;
    const int bn = blockIdx.x, bm = blockIdx.y, z = blockIdx.z;

    if (FUSECAST && z < FUSECAST) {
        const long nb     = (long)gridDim.x * gridDim.y;
        const long stride = FUSECAST * nb * 256;
        long t = ((long)z * nb + (long)bm * gridDim.x + bn) * 256 + tid;
        const long ntot = cn1 + cn2;
        for (long p = t; p < ntot; p += stride) {
            if (p < cn1) cast_pair(cs1, cd1, p);
            else         cast_pair(cs2, cd2, p - cn1);
        }
        return;
    }
    const int kz = z - FUSECAST;

    const int lane = tid & 63;
    const int wave = tid >> 6;
    const int wm   = wave >> 1, wn = wave & 1;
    const int lm   = lane & 15, lq = lane >> 4;

    const int K  = kchunk * S;
    const int k0 = kz * kchunk;

    const int rlo  = lane >> 3;                  // row within an 8-row staging chunk
    const int gsw8 = (((lane & 7) ^ rlo) << 3);  // swizzled granule -> element offset

    const __hip_bfloat16* Ag = A  + (size_t)(bm * 128) * K;
    const __hip_bfloat16* Bg = Bm + (size_t)(bn * 128) * K;

    f32x4 acc[4][4];
    #pragma unroll
    for (int i = 0; i < 4; ++i)
        #pragma unroll
        for (int j = 0; j < 4; ++j)
            acc[i][j] = (f32x4){0.f, 0.f, 0.f, 0.f};

    for (int kt = k0; kt < k0 + kchunk; kt += 64) {
        __syncthreads();
        #pragma unroll
        for (int c = 0; c < 4; ++c) {
            const int chunk = wave * 4 + c;      // 0..15, wave-uniform
            const int row   = chunk * 8 + rlo;   // local tile row 0..127
            gload_lds16(Ag + (size_t)row * K + kt + gsw8, As + chunk * 512);
            gload_lds16(Bg + (size_t)row * K + kt + gsw8, Bs + chunk * 512);
        }
        __syncthreads();
        #pragma unroll
        for (int kk = 0; kk < 2; ++kk) {
            // granule G = kk*4+lq of row lives at slot G^(row&7); row&7 == lm&7
            const int sl = (((kk * 4 + lq) ^ (lm & 7)) << 3);
            bf16x8 af[4], bq[4];
            #pragma unroll
            for (int i = 0; i < 4; ++i)
                af[i] = *(const bf16x8*)(As + (wm * 64 + i * 16 + lm) * 64 + sl);
            #pragma unroll
            for (int j = 0; j < 4; ++j)
                bq[j] = *(const bf16x8*)(Bs + (wn * 64 + j * 16 + lm) * 64 + sl);
            #pragma unroll
            for (int i = 0; i < 4; ++i)
                #pragma unroll
                for (int j = 0; j < 4; ++j)
                    acc[i][j] = __builtin_amdgcn_mfma_f32_16x16x32_bf16(af[i], bq[j], acc[i][j], 0, 0, 0);
        }
    }

    __hip_bfloat16* Pz = P + (size_t)kz * M * N;
    const int row0 = bm * 128 + wm * 64;
    const int colb = bn * 128 + wn * 64 + lm;
    #pragma unroll
    for (int j = 0; j < 4; ++j) {
        const int col = colb + j * 16;
        #pragma unroll
        for (int i = 0; i < 4; ++i)
            #pragma unroll
            for (int r = 0; r < 4; ++r) {
                const int row = row0 + i * 16 + lq * 4 + r;
                Pz[(size_t)row * N + col] = __float2bfloat16(acc[i][j][r]);
            }
    }
}

// T-collapse: za = sum_{u=1..T} w_u * relu(c_u*y + b2), where
// c_u = 1-beta1^u, w_u = (1-b2f)(1-b3f)*g_u, g_u = b2f*g_{u+1} + b3f^(T-u), g_T=1.
// Exact algebra of the s2/za double recurrence; independent terms -> ILP.
template <int TT>
__device__ __forceinline__ void tcollapse_coef(float be1, float be2, float be3,
                                               float* __restrict__ c, float* __restrict__ w) {
    float g[TT + 1];
    g[TT] = 1.f;
    float p3 = 1.f;                      // beta3^(T-u), u descending
    #pragma unroll
    for (int u = TT - 1; u >= 1; --u) {
        p3 *= be3;
        g[u] = be2 * g[u + 1] + p3;
    }
    const float s = (1.f - be2) * (1.f - be3);
    float p1 = 1.f;
    #pragma unroll
    for (int u = 1; u <= TT; ++u) {
        p1 *= be1;
        c[u - 1] = 1.f - p1;
        w[u - 1] = s * g[u];
    }
}

// Sum S bf16 split-K partials (16B loads, fp32 accumulate) + epilogue. 8 elems/thread.
// MODE 0: bf16 out = relu(sum + bias)            (layer1 -> D1)
// MODE 1: bf16 out = T-collapse(y=sum, b2)       (layer2 -> Z)
// MODE 2: f32  out = sum + (1-beta3^T)*bias      (layer3 -> s3_T)
template <int MODE>
__global__ void reduce_k(const __hip_bfloat16* __restrict__ P, const int S,
                         void* __restrict__ outv, const long MN, const int N,
                         const float* __restrict__ bias,
                         const float* __restrict__ b_taus,
                         const int* __restrict__ Tp)
{
    long i8 = (long)blockIdx.x * 256 + threadIdx.x;   // 8-element group, exact cover
    long i  = i8 * 8;
    float a[8] = {0.f, 0.f, 0.f, 0.f, 0.f, 0.f, 0.f, 0.f};
    for (int s = 0; s < S; ++s) {
        union { s16x8 p8; __hip_bfloat16 h[8]; } u;
        u.p8 = *(const s16x8*)(P + (size_t)s * MN + i);
        #pragma unroll
        for (int c = 0; c < 8; ++c) a[c] += __bfloat162float(u.h[c]);
    }
    const int col = (int)(i % N);
    float bb[8];
    #pragma unroll
    for (int c = 0; c < 8; ++c) bb[c] = bias[col + c];

    if constexpr (MODE == 0) {
        union { s16x8 p8; __hip_bfloat16 h[8]; } u;
        #pragma unroll
        for (int c = 0; c < 8; ++c)
            u.h[c] = __float2bfloat16(fmaxf(a[c] + bb[c], 0.f));
        ((s16x8*)outv)[i8] = u.p8;
    } else if constexpr (MODE == 1) {
        const int   T   = *Tp;
        const float be1 = 1.f / (1.f + expf(-b_taus[0]));
        const float be2 = 1.f / (1.f + expf(-b_taus[1]));
        const float be3 = 1.f / (1.f + expf(-b_taus[2]));
        union { s16x8 p8; __hip_bfloat16 h[8]; } u;
        if (T == 10) {                     // fast path: fully unrolled, 10 independent terms
            float c10[10], w10[10];
            tcollapse_coef<10>(be1, be2, be3, c10, w10);
            #pragma unroll
            for (int c = 0; c < 8; ++c) {
                float za = 0.f;
                #pragma unroll
                for (int t = 0; t < 10; ++t)
                    za += w10[t] * fmaxf(fmaf(c10[t], a[c], bb[c]), 0.f);
                u.h[c] = __float2bfloat16(za);
            }
        } else {                           // generic fallback (original recurrence)
            #pragma unroll
            for (int c = 0; c < 8; ++c) {
                float p1 = 1.f, s2 = 0.f, za = 0.f;
                for (int t = 0; t < T; ++t) {
                    p1 *= be1;
                    const float d2 = fmaxf(fmaf(1.f - p1, a[c], bb[c]), 0.f);
                    s2 = be2 * s2 + (1.f - be2) * d2;
                    za = be3 * za + (1.f - be3) * s2;
                }
                u.h[c] = __float2bfloat16(za);
            }
        }
        ((s16x8*)outv)[i8] = u.p8;
    } else {
        const int   T   = *Tp;
        const float be3 = 1.f / (1.f + expf(-b_taus[2]));
        float g = 0.f;
        for (int t = 0; t < T; ++t) g = be3 * g + (1.f - be3);   // 1 - beta3^T
        f32x4 o0, o1;
        o0.x = a[0] + g * bb[0]; o0.y = a[1] + g * bb[1];
        o0.z = a[2] + g * bb[2]; o0.w = a[3] + g * bb[3];
        o1.x = a[4] + g * bb[4]; o1.y = a[5] + g * bb[5];
        o1.z = a[6] + g * bb[6]; o1.w = a[7] + g * bb[7];
        ((f32x4*)outv)[i8 * 2]     = o0;
        ((f32x4*)outv)[i8 * 2 + 1] = o1;
    }
}

extern "C" void kernel_launch(void* const* d_in, const int* in_sizes, int n_in,
                              void* d_out, int out_size, void* d_ws, size_t ws_size,
                              hipStream_t stream) {
    const float* x      = (const float*)d_in[0];
    const float* W1     = (const float*)d_in[1];
    const float* b1     = (const float*)d_in[2];
    const float* W2     = (const float*)d_in[3];
    const float* b2     = (const float*)d_in[4];
    const float* W3     = (const float*)d_in[5];
    const float* b3     = (const float*)d_in[6];
    const float* b_taus = (const float*)d_in[7];
    const int*   Tp     = (const int*)d_in[8];

    const int B = 1024, DIN = 2048, H1 = 4096, H2 = 4096, DOUT = 1024;
    const long MB = 1024 * 1024;

    // Arena (108 MB high watermark): xb 0 (4MB), W1b 4 (16MB), W2b 20 (32MB),
    // W3b 52 (8MB), D1b 60 (8MB), Sb 68 (8MB), Pb 76 (32MB, shared by
    // P1/P2/P3 -- each is dead before the next GEMM writes it).
    char* ws = (char*)d_ws;
    __hip_bfloat16* xb  = (__hip_bfloat16*)(ws + 0);
    __hip_bfloat16* W1b = (__hip_bfloat16*)(ws + 4 * MB);
    __hip_bfloat16* W2b = (__hip_bfloat16*)(ws + 20 * MB);
    __hip_bfloat16* W3b = (__hip_bfloat16*)(ws + 52 * MB);
    __hip_bfloat16* D1b = (__hip_bfloat16*)(ws + 60 * MB);
    __hip_bfloat16* Sb  = (__hip_bfloat16*)(ws + 68 * MB);
    __hip_bfloat16* Pb  = (__hip_bfloat16*)(ws + 76 * MB);

    // castA: x + W1 only (gates gemm1)
    cast_a_k<<<dim3(1280), dim3(256), 0, stream>>>(x, xb, W1, W1b);

    // Layer 1 GEMM: S=4 (1024 GEMM blocks) + 1 leading cast plane (W2/W3,
    // 256 blocks). 1280 blocks at 4/CU: cast retires early, last GEMM blocks
    // backfill to 4 GEMM/CU steady state.
    gemm_btk<1><<<dim3(H1 / 128, B / 128, 1 + 4), 256, 0, stream>>>(
        xb, W1b, Pb, B, H1, DIN / 4, 4,
        W2, W2b, (long)H2 * H1 / 8, W3, W3b, (long)DOUT * H2 / 8);
    reduce_k<0><<<dim3(2048), 256, 0, stream>>>(Pb, 4, (void*)D1b, (long)B * H1, H1, b1, nullptr, nullptr);

    // Layer 2: S=4 -> 1024 blocks, clean 4/CU round.
    gemm_btk<0><<<dim3(H2 / 128, B / 128, 4), 256, 0, stream>>>(
        D1b, W2b, Pb, B, H2, H1 / 4, 4, nullptr, nullptr, 0, nullptr, nullptr, 0);
    reduce_k<1><<<dim3(2048), 256, 0, stream>>>(Pb, 4, (void*)Sb, (long)B * H2, H2, b2, b_taus, Tp);

    // Layer 3: S=16 -> 1024 blocks, 4/CU (was 512 at S=8).
    gemm_btk<0><<<dim3(DOUT / 128, B / 128, 16), 256, 0, stream>>>(
        Sb, W3b, Pb, B, DOUT, H2 / 16, 16, nullptr, nullptr, 0, nullptr, nullptr, 0);
    reduce_k<2><<<dim3(512), 256, 0, stream>>>(Pb, 16, d_out, (long)B * DOUT, DOUT, b3, b_taus, Tp);
}

// Round 4
// 260.859 us; speedup vs baseline: 1.2470x; 1.0182x over previous
//
#include <hip/hip_runtime.h>
#include <hip/hip_bf16.h>
#include <stdint.h>

#define AS_GLOBAL __attribute__((address_space(1)))
#define AS_LDS    __attribute__((address_space(3)))

typedef __attribute__((ext_vector_type(8))) short  bf16x8;
typedef __attribute__((ext_vector_type(4))) float  f32x4;
typedef __attribute__((ext_vector_type(8))) short  s16x8;

__device__ __forceinline__ void gload_lds16(const void* g, void* l) {
    __builtin_amdgcn_global_load_lds((AS_GLOBAL const void*)g, (AS_LDS void*)l, 16, 0, 0);
}

// Cast 8 fp32 -> 8 bf16 (one 16B store), pair index p into region (s,d).
__device__ __forceinline__ void cast_pair(const float* __restrict__ s,
                                          __hip_bfloat16* __restrict__ d, long p) {
    f32x4 a = ((const f32x4*)s)[p * 2];
    f32x4 b = ((const f32x4*)s)[p * 2 + 1];
    union { s16x8 p8; __hip_bfloat16 h[8]; } u;
    u.h[0] = __float2bfloat16(a.x); u.h[1] = __float2bfloat16(a.y);
    u.h[2] = __float2bfloat16(a.z); u.h[3] = __float2bfloat16(a.w);
    u.h[4] = __float2bfloat16(b.x); u.h[5] = __float2bfloat16(b.y);
    u.h[6] = __float2bfloat16(b.z); u.h[7] = __float2bfloat16(b.w);
    ((s16x8*)d)[p] = u.p8;
}

// Pure-stream cast of ALL fp32 inputs -> bf16 arena copies.
// x 262144 + W1 1048576 + W2 2097152 + W3 524288 = 3932160 pairs (180 MB moved).
// R4 rationale: R0's fused cast plane ran inside GEMM1's dispatch at a combined
// 2.4 TB/s; pure cast streams measured ~5 TB/s. Separate them.
__global__ void cast_all_k(const float* __restrict__ x,  __hip_bfloat16* __restrict__ xb,
                           const float* __restrict__ W1, __hip_bfloat16* __restrict__ W1b,
                           const float* __restrict__ W2, __hip_bfloat16* __restrict__ W2b,
                           const float* __restrict__ W3, __hip_bfloat16* __restrict__ W3b) {
    const long n0 = 262144, n1 = n0 + 1048576, n2 = n1 + 2097152, n3 = n2 + 524288;
    const long stride = 2048L * 256;
    for (long p = (long)blockIdx.x * 256 + threadIdx.x; p < n3; p += stride) {
        if      (p < n0) cast_pair(x,  xb,  p);
        else if (p < n1) cast_pair(W1, W1b, p - n0);
        else if (p < n2) cast_pair(W2, W2b, p - n1);
        else             cast_pair(W3, W3b, p - n2);
    }
}

// Split-K GEMM: P[z][M,N] = bf16( A[M,k0:k1] @ B[N,k0:k1]^T ).
// TAG distinguishes layer instances in rocprof (R4 instrumentation; three
// failed predictions came from not being able to see G1/G2/G3 separately).
// Structure: R0 body verbatim -- single-buffered 32KB LDS, global_load_lds
// both operands (reg-staging regressed 2x in R2; explicit dbuf neutral in R1;
// extra occupancy neutral-negative in R3). launch_bounds(256,4).
// 128x128 tile, BK=64, 4 waves, 4x4 16x16x32 MFMA. XOR-swizzled LDS
// (conflict-free, verified): granule g of row r stored at slot g^(r&7).
template <int TAG>
__global__ __launch_bounds__(256, 4)
void gemm_l(const __hip_bfloat16* __restrict__ A,
            const __hip_bfloat16* __restrict__ Bm,
            __hip_bfloat16* __restrict__ P,
            const int M, const int N, const int kchunk, const int S)
{
    __shared__ __hip_bfloat16 As[128 * 64];
    __shared__ __hip_bfloat16 Bs[128 * 64];

    const int tid = threadIdx.x;
    const int bn = blockIdx.x, bm = blockIdx.y, kz = blockIdx.z;

    const int lane = tid & 63;
    const int wave = tid >> 6;
    const int wm   = wave >> 1, wn = wave & 1;
    const int lm   = lane & 15, lq = lane >> 4;

    const int K  = kchunk * S;
    const int k0 = kz * kchunk;

    const int rlo  = lane >> 3;                  // row within an 8-row staging chunk
    const int gsw8 = (((lane & 7) ^ rlo) << 3);  // swizzled granule -> element offset

    const __hip_bfloat16* Ag = A  + (size_t)(bm * 128) * K;
    const __hip_bfloat16* Bg = Bm + (size_t)(bn * 128) * K;

    f32x4 acc[4][4];
    #pragma unroll
    for (int i = 0; i < 4; ++i)
        #pragma unroll
        for (int j = 0; j < 4; ++j)
            acc[i][j] = (f32x4){0.f, 0.f, 0.f, 0.f};

    for (int kt = k0; kt < k0 + kchunk; kt += 64) {
        __syncthreads();
        #pragma unroll
        for (int c = 0; c < 4; ++c) {
            const int chunk = wave * 4 + c;      // 0..15, wave-uniform
            const int row   = chunk * 8 + rlo;   // local tile row 0..127
            gload_lds16(Ag + (size_t)row * K + kt + gsw8, As + chunk * 512);
            gload_lds16(Bg + (size_t)row * K + kt + gsw8, Bs + chunk * 512);
        }
        __syncthreads();
        #pragma unroll
        for (int kk = 0; kk < 2; ++kk) {
            // granule G = kk*4+lq of row lives at slot G^(row&7); row&7 == lm&7
            const int sl = (((kk * 4 + lq) ^ (lm & 7)) << 3);
            bf16x8 af[4], bq[4];
            #pragma unroll
            for (int i = 0; i < 4; ++i)
                af[i] = *(const bf16x8*)(As + (wm * 64 + i * 16 + lm) * 64 + sl);
            #pragma unroll
            for (int j = 0; j < 4; ++j)
                bq[j] = *(const bf16x8*)(Bs + (wn * 64 + j * 16 + lm) * 64 + sl);
            #pragma unroll
            for (int i = 0; i < 4; ++i)
                #pragma unroll
                for (int j = 0; j < 4; ++j)
                    acc[i][j] = __builtin_amdgcn_mfma_f32_16x16x32_bf16(af[i], bq[j], acc[i][j], 0, 0, 0);
        }
    }

    __hip_bfloat16* Pz = P + (size_t)kz * M * N;
    const int row0 = bm * 128 + wm * 64;
    const int colb = bn * 128 + wn * 64 + lm;
    #pragma unroll
    for (int j = 0; j < 4; ++j) {
        const int col = colb + j * 16;
        #pragma unroll
        for (int i = 0; i < 4; ++i)
            #pragma unroll
            for (int r = 0; r < 4; ++r) {
                const int row = row0 + i * 16 + lq * 4 + r;
                Pz[(size_t)row * N + col] = __float2bfloat16(acc[i][j][r]);
            }
    }
}

// T-collapse: za = sum_{u=1..T} w_u * relu(c_u*y + b2), where
// c_u = 1-beta1^u, w_u = (1-b2f)(1-b3f)*g_u, g_u = b2f*g_{u+1} + b3f^(T-u), g_T=1.
template <int TT>
__device__ __forceinline__ void tcollapse_coef(float be1, float be2, float be3,
                                               float* __restrict__ c, float* __restrict__ w) {
    float g[TT + 1];
    g[TT] = 1.f;
    float p3 = 1.f;
    #pragma unroll
    for (int u = TT - 1; u >= 1; --u) {
        p3 *= be3;
        g[u] = be2 * g[u + 1] + p3;
    }
    const float s = (1.f - be2) * (1.f - be3);
    float p1 = 1.f;
    #pragma unroll
    for (int u = 1; u <= TT; ++u) {
        p1 *= be1;
        c[u - 1] = 1.f - p1;
        w[u - 1] = s * g[u];
    }
}

// Sum S bf16 split-K partials (16B loads, fp32 accumulate) + epilogue. 8 elems/thread.
// MODE 0: bf16 out = relu(sum + bias)            (layer1 -> D1)
// MODE 1: bf16 out = T-collapse(y=sum, b2)       (layer2 -> Z)
// MODE 2: f32  out = sum + (1-beta3^T)*bias      (layer3 -> s3_T)
template <int MODE>
__global__ void reduce_k(const __hip_bfloat16* __restrict__ P, const int S,
                         void* __restrict__ outv, const long MN, const int N,
                         const float* __restrict__ bias,
                         const float* __restrict__ b_taus,
                         const int* __restrict__ Tp)
{
    long i8 = (long)blockIdx.x * 256 + threadIdx.x;   // 8-element group, exact cover
    long i  = i8 * 8;
    float a[8] = {0.f, 0.f, 0.f, 0.f, 0.f, 0.f, 0.f, 0.f};
    for (int s = 0; s < S; ++s) {
        union { s16x8 p8; __hip_bfloat16 h[8]; } u;
        u.p8 = *(const s16x8*)(P + (size_t)s * MN + i);
        #pragma unroll
        for (int c = 0; c < 8; ++c) a[c] += __bfloat162float(u.h[c]);
    }
    const int col = (int)(i % N);
    float bb[8];
    #pragma unroll
    for (int c = 0; c < 8; ++c) bb[c] = bias[col + c];

    if constexpr (MODE == 0) {
        union { s16x8 p8; __hip_bfloat16 h[8]; } u;
        #pragma unroll
        for (int c = 0; c < 8; ++c)
            u.h[c] = __float2bfloat16(fmaxf(a[c] + bb[c], 0.f));
        ((s16x8*)outv)[i8] = u.p8;
    } else if constexpr (MODE == 1) {
        const int   T   = *Tp;
        const float be1 = 1.f / (1.f + expf(-b_taus[0]));
        const float be2 = 1.f / (1.f + expf(-b_taus[1]));
        const float be3 = 1.f / (1.f + expf(-b_taus[2]));
        union { s16x8 p8; __hip_bfloat16 h[8]; } u;
        if (T == 10) {                     // fast path: fully unrolled, 10 independent terms
            float c10[10], w10[10];
            tcollapse_coef<10>(be1, be2, be3, c10, w10);
            #pragma unroll
            for (int c = 0; c < 8; ++c) {
                float za = 0.f;
                #pragma unroll
                for (int t = 0; t < 10; ++t)
                    za += w10[t] * fmaxf(fmaf(c10[t], a[c], bb[c]), 0.f);
                u.h[c] = __float2bfloat16(za);
            }
        } else {                           // generic fallback (original recurrence)
            #pragma unroll
            for (int c = 0; c < 8; ++c) {
                float p1 = 1.f, s2 = 0.f, za = 0.f;
                for (int t = 0; t < T; ++t) {
                    p1 *= be1;
                    const float d2 = fmaxf(fmaf(1.f - p1, a[c], bb[c]), 0.f);
                    s2 = be2 * s2 + (1.f - be2) * d2;
                    za = be3 * za + (1.f - be3) * s2;
                }
                u.h[c] = __float2bfloat16(za);
            }
        }
        ((s16x8*)outv)[i8] = u.p8;
    } else {
        const int   T   = *Tp;
        const float be3 = 1.f / (1.f + expf(-b_taus[2]));
        float g = 0.f;
        for (int t = 0; t < T; ++t) g = be3 * g + (1.f - be3);   // 1 - beta3^T
        f32x4 o0, o1;
        o0.x = a[0] + g * bb[0]; o0.y = a[1] + g * bb[1];
        o0.z = a[2] + g * bb[2]; o0.w = a[3] + g * bb[3];
        o1.x = a[4] + g * bb[4]; o1.y = a[5] + g * bb[5];
        o1.z = a[6] + g * bb[6]; o1.w = a[7] + g * bb[7];
        ((f32x4*)outv)[i8 * 2]     = o0;
        ((f32x4*)outv)[i8 * 2 + 1] = o1;
    }
}

extern "C" void kernel_launch(void* const* d_in, const int* in_sizes, int n_in,
                              void* d_out, int out_size, void* d_ws, size_t ws_size,
                              hipStream_t stream) {
    const float* x      = (const float*)d_in[0];
    const float* W1     = (const float*)d_in[1];
    const float* b1     = (const float*)d_in[2];
    const float* W2     = (const float*)d_in[3];
    const float* b2     = (const float*)d_in[4];
    const float* W3     = (const float*)d_in[5];
    const float* b3     = (const float*)d_in[6];
    const float* b_taus = (const float*)d_in[7];
    const int*   Tp     = (const int*)d_in[8];

    const int B = 1024, DIN = 2048, H1 = 4096, H2 = 4096, DOUT = 1024;
    const long MB = 1024 * 1024;

    // Arena (108 MB): xb 0 (4MB), W1b 4 (16MB), W2b 20 (32MB), W3b 52 (8MB),
    // D1b 60 (8MB), Sb 68 (8MB), Pb 76 (32MB, shared by all split-K phases).
    char* ws = (char*)d_ws;
    __hip_bfloat16* xb  = (__hip_bfloat16*)(ws + 0);
    __hip_bfloat16* W1b = (__hip_bfloat16*)(ws + 4 * MB);
    __hip_bfloat16* W2b = (__hip_bfloat16*)(ws + 20 * MB);
    __hip_bfloat16* W3b = (__hip_bfloat16*)(ws + 52 * MB);
    __hip_bfloat16* D1b = (__hip_bfloat16*)(ws + 60 * MB);
    __hip_bfloat16* Sb  = (__hip_bfloat16*)(ws + 68 * MB);
    __hip_bfloat16* Pb  = (__hip_bfloat16*)(ws + 76 * MB);

    // Pure cast stream: everything fp32 -> bf16 in one dispatch (2048 blocks).
    cast_all_k<<<dim3(2048), dim3(256), 0, stream>>>(x, xb, W1, W1b, W2, W2b, W3, W3b);

    // Layer 1: S=2 (512 blocks). Pure GEMM, operands L3-hot from the cast.
    gemm_l<1><<<dim3(H1 / 128, B / 128, 2), 256, 0, stream>>>(
        xb, W1b, Pb, B, H1, DIN / 2, 2);
    reduce_k<0><<<dim3(2048), 256, 0, stream>>>(Pb, 2, (void*)D1b, (long)B * H1, H1, b1, nullptr, nullptr);

    // Layer 2: S=4 (1024 blocks).
    gemm_l<2><<<dim3(H2 / 128, B / 128, 4), 256, 0, stream>>>(
        D1b, W2b, Pb, B, H2, H1 / 4, 4);
    reduce_k<1><<<dim3(2048), 256, 0, stream>>>(Pb, 4, (void*)Sb, (long)B * H2, H2, b2, b_taus, Tp);

    // Layer 3: S=8 (512 blocks).
    gemm_l<3><<<dim3(DOUT / 128, B / 128, 8), 256, 0, stream>>>(
        Sb, W3b, Pb, B, DOUT, H2 / 8, 8);
    reduce_k<2><<<dim3(512), 256, 0, stream>>>(Pb, 8, d_out, (long)B * DOUT, DOUT, b3, b_taus, Tp);
}